// Round 1
// baseline (5039.520 us; speedup 1.0000x reference)
//
#include <hip/hip_runtime.h>
#include <math.h>

#define B_ 16
#define L_ 1024
#define M_TOT (B_*L_)   // 16384

__device__ __forceinline__ float wave_reduce_sum(float v) {
#pragma unroll
  for (int o = 32; o >= 1; o >>= 1) v += __shfl_xor(v, o, 64);
  return v;
}

// ---------------- featurize: z (B,L,64), boundary (B,L) ----------------
__global__ __launch_bounds__(64) void featurize_kernel(
    const float* __restrict__ pts, const float* __restrict__ fs, const float* __restrict__ ft,
    const float* __restrict__ w_space, const float* __restrict__ b_space,
    const float* __restrict__ w_time, const float* __restrict__ b_time,
    const float* __restrict__ w_fout, const float* __restrict__ b_fout,
    const float* __restrict__ w_gate, const float* __restrict__ b_gate,
    float* __restrict__ z, int* __restrict__ boundary)
{
  const int p = blockIdx.x;
  const int d = threadIdx.x;
  const float TWO_PI = 6.283185307179586f;
  __shared__ float feat[32];
  __shared__ float tfeat[16];
  __shared__ float g96[96];
  const float x = pts[p*3+0], y = pts[p*3+1], t = pts[p*3+2];
  if (d < 16) {
    float sp = (x*fs[d] + y*fs[16+d]) * TWO_PI;
    feat[d]    = sinf(sp);
    feat[16+d] = cosf(sp);
  } else if (d < 24) {
    int r = d - 16;
    float tp = t * ft[r] * TWO_PI;
    tfeat[r]   = sinf(tp);
    tfeat[8+r] = cosf(tp);
  }
  __syncthreads();
  float sf = b_space[d];
#pragma unroll
  for (int k2 = 0; k2 < 32; ++k2) sf = fmaf(feat[k2], w_space[k2*64+d], sf);
  g96[d] = sf;
  if (d < 32) {
    float tf = b_time[d];
#pragma unroll
    for (int k2 = 0; k2 < 16; ++k2) tf = fmaf(tfeat[k2], w_time[k2*32+d], tf);
    g96[64+d] = tf;
  }
  __syncthreads();
  float zv = b_fout[d];
#pragma unroll
  for (int k2 = 0; k2 < 96; ++k2) zv = fmaf(g96[k2], w_fout[k2*64+d], zv);
  z[(size_t)p*64+d] = zv;
  float gv = wave_reduce_sum(zv * w_gate[d]);
  if (d == 0) {
    float logit = gv + b_gate[0];
    float gate = 1.0f / (1.0f + expf(-logit));
    int bnd = (gate > 0.5f) ? 1 : 0;
    if ((p & (L_-1)) == 0) bnd = 1;
    boundary[p] = bnd;
  }
}

// ---------------- scan: seg_id, seg_start, n_seg ----------------
__global__ __launch_bounds__(1024) void scan_kernel(const int* __restrict__ boundary,
    int* __restrict__ seg_id, int* __restrict__ seg_start, int* __restrict__ n_seg)
{
  __shared__ int sc[1024];
  const int b = blockIdx.x, l = threadIdx.x;
  const int v = boundary[b*L_ + l];
  sc[l] = v;
  __syncthreads();
  for (int off = 1; off < 1024; off <<= 1) {
    int add = (l >= off) ? sc[l - off] : 0;
    __syncthreads();
    sc[l] += add;
    __syncthreads();
  }
  const int sid = sc[l] - 1;
  seg_id[b*L_ + l] = sid;
  if (v) seg_start[b*(L_+1) + sid] = l;
  if (l == L_-1) {
    n_seg[b] = sid + 1;
    seg_start[b*(L_+1) + sid + 1] = L_;
  }
}

// ---------------- generic GEMM: C = act(A[M,K] @ W[K,N] + bias) ----------------
template<int N, int K, bool RELU>
__global__ __launch_bounds__(256) void gemm_kernel(
    const float* __restrict__ A, const float* __restrict__ W,
    const float* __restrict__ bias, float* __restrict__ C)
{
  constexpr int BM = 64, BK = 32;
  constexpr int TN = N / 16;
  __shared__ float As[BM][BK + 4];
  const int tid = threadIdx.x;
  const int row0 = blockIdx.x * BM;
  const int ty = tid >> 4, tx = tid & 15;
  float acc[4][TN];
#pragma unroll
  for (int i = 0; i < 4; ++i)
#pragma unroll
    for (int j = 0; j < TN; ++j) acc[i][j] = 0.f;
  const int lr = tid >> 2;
  const int lc = (tid & 3) * 8;
  for (int k0 = 0; k0 < K; k0 += BK) {
    const float4* src = reinterpret_cast<const float4*>(A + (size_t)(row0 + lr)*K + k0 + lc);
    float4 a0 = src[0], a1 = src[1];
    *reinterpret_cast<float4*>(&As[lr][lc])   = a0;
    *reinterpret_cast<float4*>(&As[lr][lc+4]) = a1;
    __syncthreads();
#pragma unroll 8
    for (int kk = 0; kk < BK; ++kk) {
      float a[4];
#pragma unroll
      for (int i = 0; i < 4; ++i) a[i] = As[ty*4+i][kk];
      const float4* wr = reinterpret_cast<const float4*>(W + (size_t)(k0+kk)*N + tx*TN);
      float w[TN];
#pragma unroll
      for (int j4 = 0; j4 < TN/4; ++j4) {
        float4 wv = wr[j4];
        w[j4*4+0]=wv.x; w[j4*4+1]=wv.y; w[j4*4+2]=wv.z; w[j4*4+3]=wv.w;
      }
#pragma unroll
      for (int i = 0; i < 4; ++i)
#pragma unroll
        for (int j = 0; j < TN; ++j)
          acc[i][j] = fmaf(a[i], w[j], acc[i][j]);
    }
    __syncthreads();
  }
#pragma unroll
  for (int i = 0; i < 4; ++i) {
    const int row = row0 + ty*4 + i;
#pragma unroll
    for (int j = 0; j < TN; ++j) {
      const int col = tx*TN + j;
      float v2 = acc[i][j] + bias[col];
      if (RELU) v2 = fmaxf(v2, 0.f);
      C[(size_t)row*N + col] = v2;
    }
  }
}

// ---------------- segment attention (block-diagonal, exact) ----------------
__global__ __launch_bounds__(256) void seg_attn_kernel(
    const float* __restrict__ q, const float* __restrict__ k, const float* __restrict__ v,
    const int* __restrict__ seg_id, const int* __restrict__ seg_start,
    float* __restrict__ ao)
{
  const int idx = blockIdx.x * 256 + threadIdx.x;  // ((b*L + pt)*2 + h)
  const int h  = idx & 1;
  const int pt = (idx >> 1) & (L_-1);
  const int b  = idx >> 11;
  const float scale = sqrtf(32.0f);
  const size_t rowq = (size_t)(b*L_ + pt)*64 + h*32;
  float qv[32];
  {
    const float4* qp = reinterpret_cast<const float4*>(q + rowq);
#pragma unroll
    for (int j4 = 0; j4 < 8; ++j4) {
      float4 t4 = qp[j4];
      qv[j4*4+0]=t4.x; qv[j4*4+1]=t4.y; qv[j4*4+2]=t4.z; qv[j4*4+3]=t4.w;
    }
  }
  const int s  = seg_id[b*L_ + pt];
  const int j0 = seg_start[b*(L_+1) + s];
  const int j1 = seg_start[b*(L_+1) + s + 1];
  float m = -INFINITY, lsum = 0.f;
  float acc[32];
#pragma unroll
  for (int d = 0; d < 32; ++d) acc[d] = 0.f;
  for (int j = j0; j < j1; ++j) {
    const size_t rk = (size_t)(b*L_ + j)*64 + h*32;
    const float4* kp = reinterpret_cast<const float4*>(k + rk);
    float dot = 0.f;
#pragma unroll
    for (int j4 = 0; j4 < 8; ++j4) {
      float4 t4 = kp[j4];
      dot = fmaf(qv[j4*4+0], t4.x, dot);
      dot = fmaf(qv[j4*4+1], t4.y, dot);
      dot = fmaf(qv[j4*4+2], t4.z, dot);
      dot = fmaf(qv[j4*4+3], t4.w, dot);
    }
    const float scr = dot / scale;
    const float nm = fmaxf(m, scr);
    const float ea = (m > -1e37f) ? expf(m - nm) : 0.f;
    const float p  = expf(scr - nm);
    lsum = lsum * ea + p;
    const float4* vp = reinterpret_cast<const float4*>(v + rk);
#pragma unroll
    for (int j4 = 0; j4 < 8; ++j4) {
      float4 t4 = vp[j4];
      acc[j4*4+0] = acc[j4*4+0]*ea + p*t4.x;
      acc[j4*4+1] = acc[j4*4+1]*ea + p*t4.y;
      acc[j4*4+2] = acc[j4*4+2]*ea + p*t4.z;
      acc[j4*4+3] = acc[j4*4+3]*ea + p*t4.w;
    }
    m = nm;
  }
  const float inv = 1.0f / lsum;
  float* op = ao + rowq;
#pragma unroll
  for (int d = 0; d < 32; ++d) op[d] = acc[d] * inv;
}

// ---------------- global attention: valid queries attend keys j<ns ----------------
__global__ __launch_bounds__(256) void glb_attn_kernel(
    const float* __restrict__ q, const float* __restrict__ k, const float* __restrict__ v,
    const int* __restrict__ n_seg, float* __restrict__ ao)
{
  const int b  = blockIdx.x >> 10;
  const int qi = blockIdx.x & (L_-1);
  const int ns = n_seg[b];
  if (qi >= ns) return;
  const int wv = threadIdx.x >> 6;   // head 0..3
  const int lane = threadIdx.x & 63;
  const float scale = sqrtf(32.0f);
  const size_t rowq = (size_t)(b*L_ + qi)*128 + wv*32;
  float qv[32];
  {
    const float4* qp = reinterpret_cast<const float4*>(q + rowq);
#pragma unroll
    for (int j4 = 0; j4 < 8; ++j4) {
      float4 t4 = qp[j4];
      qv[j4*4+0]=t4.x; qv[j4*4+1]=t4.y; qv[j4*4+2]=t4.z; qv[j4*4+3]=t4.w;
    }
  }
  float m = -INFINITY, lsum = 0.f;
  float acc[32];
#pragma unroll
  for (int d = 0; d < 32; ++d) acc[d] = 0.f;
  for (int j = lane; j < ns; j += 64) {
    const size_t rk = (size_t)(b*L_ + j)*128 + wv*32;
    const float4* kp = reinterpret_cast<const float4*>(k + rk);
    float dot = 0.f;
#pragma unroll
    for (int j4 = 0; j4 < 8; ++j4) {
      float4 t4 = kp[j4];
      dot = fmaf(qv[j4*4+0], t4.x, dot);
      dot = fmaf(qv[j4*4+1], t4.y, dot);
      dot = fmaf(qv[j4*4+2], t4.z, dot);
      dot = fmaf(qv[j4*4+3], t4.w, dot);
    }
    const float scr = dot / scale;
    const float nm = fmaxf(m, scr);
    const float ea = (m > -1e37f) ? expf(m - nm) : 0.f;
    const float p  = expf(scr - nm);
    lsum = lsum * ea + p;
    const float4* vp = reinterpret_cast<const float4*>(v + rk);
#pragma unroll
    for (int j4 = 0; j4 < 8; ++j4) {
      float4 t4 = vp[j4];
      acc[j4*4+0] = acc[j4*4+0]*ea + p*t4.x;
      acc[j4*4+1] = acc[j4*4+1]*ea + p*t4.y;
      acc[j4*4+2] = acc[j4*4+2]*ea + p*t4.z;
      acc[j4*4+3] = acc[j4*4+3]*ea + p*t4.w;
    }
    m = nm;
  }
  // butterfly merge of (m,lsum,acc[32]) across 64 lanes
#pragma unroll
  for (int off = 1; off < 64; off <<= 1) {
    float om = __shfl_xor(m, off, 64);
    float ol = __shfl_xor(lsum, off, 64);
    float nm = fmaxf(m, om);
    float ea = (m  > -1e37f) ? expf(m  - nm) : 0.f;
    float eb = (om > -1e37f) ? expf(om - nm) : 0.f;
    lsum = lsum*ea + ol*eb;
#pragma unroll
    for (int d = 0; d < 32; ++d) {
      float oa = __shfl_xor(acc[d], off, 64);
      acc[d] = acc[d]*ea + oa*eb;
    }
    m = nm;
  }
  if (lane < 32) {
    float outv = 0.f;
#pragma unroll
    for (int d = 0; d < 32; ++d) if (lane == d) outv = acc[d];  // static idx, no scratch
    ao[(size_t)(b*L_+qi)*128 + wv*32 + lane] = outv / lsum;
  }
}

// ---------------- LN(x + r)*g + b, in place into x ----------------
template<int D>
__global__ __launch_bounds__(D) void ln_res_kernel(
    float* __restrict__ x, const float* __restrict__ r,
    const float* __restrict__ gam, const float* __restrict__ bet)
{
  const size_t row = blockIdx.x;
  const int d = threadIdx.x;
  float val = x[row*D + d] + r[row*D + d];
  float s = wave_reduce_sum(val);
  __shared__ float red[4];
  if constexpr (D == 128) {
    if ((d & 63) == 0) red[d >> 6] = s;
    __syncthreads();
    s = red[0] + red[1];
  }
  const float mean = s / (float)D;
  const float dv = val - mean;
  float s2 = wave_reduce_sum(dv*dv);
  if constexpr (D == 128) {
    if ((d & 63) == 0) red[2 + (d >> 6)] = s2;
    __syncthreads();
    s2 = red[2] + red[3];
  }
  x[row*D + d] = dv * rsqrtf(s2 / (float)D + 1e-5f) * gam[d] + bet[d];
}

// ---------------- segment mean pooling ----------------
__global__ __launch_bounds__(64) void pool_kernel(
    const float* __restrict__ h, const int* __restrict__ seg_start,
    const int* __restrict__ n_seg, float* __restrict__ mean)
{
  const int b = blockIdx.x >> 10;
  const int s = blockIdx.x & (L_-1);
  const int d = threadIdx.x;
  float out = 0.f;
  if (s < n_seg[b]) {
    const int j0 = seg_start[b*(L_+1)+s], j1 = seg_start[b*(L_+1)+s+1];
    float acc = 0.f;
    for (int j = j0; j < j1; ++j) acc += h[(size_t)(b*L_+j)*64 + d];
    out = acc / (float)(j1 - j0);
  }
  mean[(size_t)(b*L_+s)*64 + d] = out;
}

// ---------------- final: pooled @ fin_w + fin_b ----------------
__global__ __launch_bounds__(128) void final_kernel(
    const float* __restrict__ g, const float* __restrict__ semb,
    const int* __restrict__ n_seg, const float* __restrict__ fin_w,
    const float* __restrict__ fin_b, float* __restrict__ out)
{
  const int b = blockIdx.x, d = threadIdx.x;
  const int ns = n_seg[b];
  __shared__ float pl[128];
  float pooled;
  if (ns == 1) pooled = semb[(size_t)(b*L_)*128 + d];
  else {
    float acc = 0.f;
    for (int i = 0; i < ns; ++i) acc += g[(size_t)(b*L_+i)*128 + d];
    pooled = acc / (float)ns;
  }
  pl[d] = pooled;
  __syncthreads();
  float o = fin_b[d];
#pragma unroll 8
  for (int k2 = 0; k2 < 128; ++k2) o = fmaf(pl[k2], fin_w[k2*128+d], o);
  out[b*128+d] = o;
}

extern "C" void kernel_launch(void* const* d_in, const int* in_sizes, int n_in,
                              void* d_out, int out_size, void* d_ws, size_t ws_size,
                              hipStream_t stream) {
  const float* pts     = (const float*)d_in[0];
  const float* fs      = (const float*)d_in[1];
  const float* ft      = (const float*)d_in[2];
  const float* w_space = (const float*)d_in[3];
  const float* b_space = (const float*)d_in[4];
  const float* w_time  = (const float*)d_in[5];
  const float* b_time  = (const float*)d_in[6];
  const float* w_fout  = (const float*)d_in[7];
  const float* b_fout  = (const float*)d_in[8];
  const float* w_gate  = (const float*)d_in[9];
  const float* b_gate  = (const float*)d_in[10];
  const float* seg_attn_w = (const float*)d_in[11];
  const float* seg_attn_b = (const float*)d_in[12];
  const float* seg_ln_g   = (const float*)d_in[13];
  const float* seg_ln_b   = (const float*)d_in[14];
  const float* seg_ff1_w  = (const float*)d_in[15];
  const float* seg_ff1_b  = (const float*)d_in[16];
  const float* seg_ff2_w  = (const float*)d_in[17];
  const float* seg_ff2_b  = (const float*)d_in[18];
  const float* glb_attn_w = (const float*)d_in[19];
  const float* glb_attn_b = (const float*)d_in[20];
  const float* glb_ln_g   = (const float*)d_in[21];
  const float* glb_ln_b   = (const float*)d_in[22];
  const float* glb_ff1_w  = (const float*)d_in[23];
  const float* glb_ff1_b  = (const float*)d_in[24];
  const float* glb_ff2_w  = (const float*)d_in[25];
  const float* glb_ff2_b  = (const float*)d_in[26];
  const float* up_w    = (const float*)d_in[27];
  const float* up_b    = (const float*)d_in[28];
  const float* fin_w   = (const float*)d_in[29];
  const float* fin_b   = (const float*)d_in[30];

  char* ws = (char*)d_ws;
  float* zx   = (float*)(ws);                         // 16384*64  = 4MB
  float* qb   = (float*)(ws + ((size_t)4  << 20));    // 16384*128 = 8MB
  float* kb   = (float*)(ws + ((size_t)12 << 20));    // 8MB
  float* vb   = (float*)(ws + ((size_t)20 << 20));    // 8MB (also reused as pooled-mean)
  float* aob  = (float*)(ws + ((size_t)28 << 20));    // 8MB
  float* xg   = (float*)(ws + ((size_t)36 << 20));    // 8MB
  float* semb = (float*)(ws + ((size_t)44 << 20));    // 8MB
  float* tmp  = qb;                                   // 16MB alias over q..k (safe: disjoint lifetimes)
  int* boundary  = (int*)(ws + ((size_t)52 << 20));
  int* seg_id    = boundary + M_TOT;
  int* seg_start = seg_id + M_TOT;
  int* n_seg     = seg_start + B_*(L_+1);

  featurize_kernel<<<M_TOT, 64, 0, stream>>>(pts, fs, ft, w_space, b_space, w_time, b_time,
                                             w_fout, b_fout, w_gate, b_gate, zx, boundary);
  scan_kernel<<<B_, 1024, 0, stream>>>(boundary, seg_id, seg_start, n_seg);

  // ---- segment-level encoder (D=64, H=2, FF=128) ----
  for (int l = 0; l < 2; ++l) {
    const float* aw = seg_attn_w + (size_t)l*4*64*64;
    const float* ab = seg_attn_b + (size_t)l*4*64;
    gemm_kernel<64,64,false><<<256,256,0,stream>>>(zx, aw + 0*4096, ab + 0,   qb);
    gemm_kernel<64,64,false><<<256,256,0,stream>>>(zx, aw + 1*4096, ab + 64,  kb);
    gemm_kernel<64,64,false><<<256,256,0,stream>>>(zx, aw + 2*4096, ab + 128, vb);
    seg_attn_kernel<<<(M_TOT*2)/256, 256, 0, stream>>>(qb, kb, vb, seg_id, seg_start, aob);
    gemm_kernel<64,64,false><<<256,256,0,stream>>>(aob, aw + 3*4096, ab + 192, tmp);
    ln_res_kernel<64><<<M_TOT, 64, 0, stream>>>(zx, tmp, seg_ln_g + l*128, seg_ln_b + l*128);
    gemm_kernel<128,64,true><<<256,256,0,stream>>>(zx, seg_ff1_w + (size_t)l*64*128, seg_ff1_b + l*128, tmp);
    gemm_kernel<64,128,false><<<256,256,0,stream>>>(tmp, seg_ff2_w + (size_t)l*128*64, seg_ff2_b + l*64, aob);
    ln_res_kernel<64><<<M_TOT, 64, 0, stream>>>(zx, aob, seg_ln_g + l*128 + 64, seg_ln_b + l*128 + 64);
  }

  // ---- pooling + up-projection ----
  pool_kernel<<<M_TOT, 64, 0, stream>>>(zx, seg_start, n_seg, vb);
  gemm_kernel<128,64,false><<<256,256,0,stream>>>(vb, up_w, up_b, semb);
  hipMemcpyAsync(xg, semb, (size_t)M_TOT*128*4, hipMemcpyDeviceToDevice, stream);

  // ---- global-level encoder (D=128, H=4, FF=256) ----
  for (int l = 0; l < 2; ++l) {
    const float* aw = glb_attn_w + (size_t)l*4*128*128;
    const float* ab = glb_attn_b + (size_t)l*4*128;
    gemm_kernel<128,128,false><<<256,256,0,stream>>>(xg, aw + 0*16384, ab + 0,   qb);
    gemm_kernel<128,128,false><<<256,256,0,stream>>>(xg, aw + 1*16384, ab + 128, kb);
    gemm_kernel<128,128,false><<<256,256,0,stream>>>(xg, aw + 2*16384, ab + 256, vb);
    glb_attn_kernel<<<M_TOT, 256, 0, stream>>>(qb, kb, vb, n_seg, aob);
    gemm_kernel<128,128,false><<<256,256,0,stream>>>(aob, aw + 3*16384, ab + 384, tmp);
    ln_res_kernel<128><<<M_TOT, 128, 0, stream>>>(xg, tmp, glb_ln_g + l*256, glb_ln_b + l*256);
    gemm_kernel<256,128,true><<<256,256,0,stream>>>(xg, glb_ff1_w + (size_t)l*128*256, glb_ff1_b + l*256, tmp);
    gemm_kernel<128,256,false><<<256,256,0,stream>>>(tmp, glb_ff2_w + (size_t)l*256*128, glb_ff2_b + l*128, aob);
    ln_res_kernel<128><<<M_TOT, 128, 0, stream>>>(xg, aob, glb_ln_g + l*256 + 128, glb_ln_b + l*256 + 128);
  }

  final_kernel<<<B_, 128, 0, stream>>>(xg, semb, n_seg, fin_w, fin_b, (float*)d_out);
}

// Round 2
// 1513.452 us; speedup vs baseline: 3.3298x; 3.3298x over previous
//
#include <hip/hip_runtime.h>
#include <math.h>

#define B_ 16
#define L_ 1024
#define M_TOT (B_*L_)   // 16384

__device__ __forceinline__ float wave_reduce_sum(float v) {
#pragma unroll
  for (int o = 32; o >= 1; o >>= 1) v += __shfl_xor(v, o, 64);
  return v;
}

// ---------------- featurize: z (B,L,64), boundary (B,L) ----------------
__global__ __launch_bounds__(64) void featurize_kernel(
    const float* __restrict__ pts, const float* __restrict__ fs, const float* __restrict__ ft,
    const float* __restrict__ w_space, const float* __restrict__ b_space,
    const float* __restrict__ w_time, const float* __restrict__ b_time,
    const float* __restrict__ w_fout, const float* __restrict__ b_fout,
    const float* __restrict__ w_gate, const float* __restrict__ b_gate,
    float* __restrict__ z, int* __restrict__ boundary)
{
  const int p = blockIdx.x;
  const int d = threadIdx.x;
  const float TWO_PI = 6.283185307179586f;
  __shared__ float feat[32];
  __shared__ float tfeat[16];
  __shared__ float g96[96];
  const float x = pts[p*3+0], y = pts[p*3+1], t = pts[p*3+2];
  if (d < 16) {
    float sp = (x*fs[d] + y*fs[16+d]) * TWO_PI;
    feat[d]    = sinf(sp);
    feat[16+d] = cosf(sp);
  } else if (d < 24) {
    int r = d - 16;
    float tp = t * ft[r] * TWO_PI;
    tfeat[r]   = sinf(tp);
    tfeat[8+r] = cosf(tp);
  }
  __syncthreads();
  float sf = b_space[d];
#pragma unroll
  for (int k2 = 0; k2 < 32; ++k2) sf = fmaf(feat[k2], w_space[k2*64+d], sf);
  g96[d] = sf;
  if (d < 32) {
    float tf = b_time[d];
#pragma unroll
    for (int k2 = 0; k2 < 16; ++k2) tf = fmaf(tfeat[k2], w_time[k2*32+d], tf);
    g96[64+d] = tf;
  }
  __syncthreads();
  float zv = b_fout[d];
#pragma unroll
  for (int k2 = 0; k2 < 96; ++k2) zv = fmaf(g96[k2], w_fout[k2*64+d], zv);
  z[(size_t)p*64+d] = zv;
  float gv = wave_reduce_sum(zv * w_gate[d]);
  if (d == 0) {
    float logit = gv + b_gate[0];
    float gate = 1.0f / (1.0f + expf(-logit));
    int bnd = (gate > 0.5f) ? 1 : 0;
    if ((p & (L_-1)) == 0) bnd = 1;
    boundary[p] = bnd;
  }
}

// ---------------- scan: seg_id, seg_start, n_seg ----------------
__global__ __launch_bounds__(1024) void scan_kernel(const int* __restrict__ boundary,
    int* __restrict__ seg_id, int* __restrict__ seg_start, int* __restrict__ n_seg)
{
  __shared__ int sc[1024];
  const int b = blockIdx.x, l = threadIdx.x;
  const int v = boundary[b*L_ + l];
  sc[l] = v;
  __syncthreads();
  for (int off = 1; off < 1024; off <<= 1) {
    int add = (l >= off) ? sc[l - off] : 0;
    __syncthreads();
    sc[l] += add;
    __syncthreads();
  }
  const int sid = sc[l] - 1;
  seg_id[b*L_ + l] = sid;
  if (v) seg_start[b*(L_+1) + sid] = l;
  if (l == L_-1) {
    n_seg[b] = sid + 1;
    seg_start[b*(L_+1) + sid + 1] = L_;
  }
}

// ---------------- generic GEMM: C = act(A[M,K] @ W[K,N] + bias) ----------------
// GATED: skip blocks whose 64-row stripe lies entirely in the invalid region
// (i >= n_seg[b]); stale rows there are never consumed by any valid output.
template<int N, int K, bool RELU, bool GATED>
__global__ __launch_bounds__(256) void gemm_kernel(
    const float* __restrict__ A, const float* __restrict__ W,
    const float* __restrict__ bias, float* __restrict__ C,
    const int* __restrict__ nseg)
{
  constexpr int BM = 64, BK = 32;
  constexpr int TN = N / 16;
  const int row0 = blockIdx.x * BM;
  if (GATED) {
    const int b = row0 >> 10, i0 = row0 & (L_-1);
    if (i0 >= nseg[b]) return;
  }
  __shared__ float As[BM][BK + 4];
  const int tid = threadIdx.x;
  const int ty = tid >> 4, tx = tid & 15;
  float acc[4][TN];
#pragma unroll
  for (int i = 0; i < 4; ++i)
#pragma unroll
    for (int j = 0; j < TN; ++j) acc[i][j] = 0.f;
  const int lr = tid >> 2;
  const int lc = (tid & 3) * 8;
  for (int k0 = 0; k0 < K; k0 += BK) {
    const float4* src = reinterpret_cast<const float4*>(A + (size_t)(row0 + lr)*K + k0 + lc);
    float4 a0 = src[0], a1 = src[1];
    *reinterpret_cast<float4*>(&As[lr][lc])   = a0;
    *reinterpret_cast<float4*>(&As[lr][lc+4]) = a1;
    __syncthreads();
#pragma unroll 8
    for (int kk = 0; kk < BK; ++kk) {
      float a[4];
#pragma unroll
      for (int i = 0; i < 4; ++i) a[i] = As[ty*4+i][kk];
      const float4* wr = reinterpret_cast<const float4*>(W + (size_t)(k0+kk)*N + tx*TN);
      float w[TN];
#pragma unroll
      for (int j4 = 0; j4 < TN/4; ++j4) {
        float4 wv = wr[j4];
        w[j4*4+0]=wv.x; w[j4*4+1]=wv.y; w[j4*4+2]=wv.z; w[j4*4+3]=wv.w;
      }
#pragma unroll
      for (int i = 0; i < 4; ++i)
#pragma unroll
        for (int j = 0; j < TN; ++j)
          acc[i][j] = fmaf(a[i], w[j], acc[i][j]);
    }
    __syncthreads();
  }
#pragma unroll
  for (int i = 0; i < 4; ++i) {
    const int row = row0 + ty*4 + i;
#pragma unroll
    for (int j = 0; j < TN; ++j) {
      const int col = tx*TN + j;
      float v2 = acc[i][j] + bias[col];
      if (RELU) v2 = fmaxf(v2, 0.f);
      C[(size_t)row*N + col] = v2;
    }
  }
}

// ---------------- segment attention (block-diagonal, exact) ----------------
__global__ __launch_bounds__(256) void seg_attn_kernel(
    const float* __restrict__ q, const float* __restrict__ k, const float* __restrict__ v,
    const int* __restrict__ seg_id, const int* __restrict__ seg_start,
    float* __restrict__ ao)
{
  const int idx = blockIdx.x * 256 + threadIdx.x;  // ((b*L + pt)*2 + h)
  const int h  = idx & 1;
  const int pt = (idx >> 1) & (L_-1);
  const int b  = idx >> 11;
  const float scale = 0.17677669529663687f; // 1/sqrt(32)
  const size_t rowq = (size_t)(b*L_ + pt)*64 + h*32;
  float qv[32];
  {
    const float4* qp = reinterpret_cast<const float4*>(q + rowq);
#pragma unroll
    for (int j4 = 0; j4 < 8; ++j4) {
      float4 t4 = qp[j4];
      qv[j4*4+0]=t4.x; qv[j4*4+1]=t4.y; qv[j4*4+2]=t4.z; qv[j4*4+3]=t4.w;
    }
  }
  const int s  = seg_id[b*L_ + pt];
  const int j0 = seg_start[b*(L_+1) + s];
  const int j1 = seg_start[b*(L_+1) + s + 1];
  float m = -INFINITY, lsum = 0.f;
  float acc[32];
#pragma unroll
  for (int d = 0; d < 32; ++d) acc[d] = 0.f;
  for (int j = j0; j < j1; ++j) {
    const size_t rk = (size_t)(b*L_ + j)*64 + h*32;
    const float4* kp = reinterpret_cast<const float4*>(k + rk);
    float dot = 0.f;
#pragma unroll
    for (int j4 = 0; j4 < 8; ++j4) {
      float4 t4 = kp[j4];
      dot = fmaf(qv[j4*4+0], t4.x, dot);
      dot = fmaf(qv[j4*4+1], t4.y, dot);
      dot = fmaf(qv[j4*4+2], t4.z, dot);
      dot = fmaf(qv[j4*4+3], t4.w, dot);
    }
    const float scr = dot * scale;
    if (scr > m) {
      const float ea = (m > -1e37f) ? __expf(m - scr) : 0.f;
      lsum *= ea;
#pragma unroll
      for (int d = 0; d < 32; ++d) acc[d] *= ea;
      m = scr;
    }
    const float p = __expf(scr - m);
    lsum += p;
    const float4* vp = reinterpret_cast<const float4*>(v + rk);
#pragma unroll
    for (int j4 = 0; j4 < 8; ++j4) {
      float4 t4 = vp[j4];
      acc[j4*4+0] = fmaf(p, t4.x, acc[j4*4+0]);
      acc[j4*4+1] = fmaf(p, t4.y, acc[j4*4+1]);
      acc[j4*4+2] = fmaf(p, t4.z, acc[j4*4+2]);
      acc[j4*4+3] = fmaf(p, t4.w, acc[j4*4+3]);
    }
  }
  const float inv = 1.0f / lsum;
  float* op = ao + rowq;
#pragma unroll
  for (int d = 0; d < 32; ++d) op[d] = acc[d] * inv;
}

// ---------------- global attention v2: thread-per-query, K/V tiles in LDS ----
// grid: blockIdx.x = ((b*4 + h)*4 + qt), qt covers 256 queries
__global__ __launch_bounds__(256) void glb_attn_kernel(
    const float* __restrict__ q, const float* __restrict__ k, const float* __restrict__ v,
    const int* __restrict__ n_seg, float* __restrict__ ao)
{
  const int qt = blockIdx.x & 3;
  const int h  = (blockIdx.x >> 2) & 3;
  const int b  = blockIdx.x >> 4;
  const int ns = n_seg[b];
  if (qt*256 >= ns) return;               // block-uniform exit
  const int qi = qt*256 + (int)threadIdx.x;
  const bool active = qi < ns;
  __shared__ float Ks[64][32];
  __shared__ float Vs[64][32];
  const float scale = 0.17677669529663687f; // 1/sqrt(32)
  float qv[32];
  if (active) {
    const float4* qp = reinterpret_cast<const float4*>(q + (size_t)(b*L_+qi)*128 + h*32);
#pragma unroll
    for (int j4 = 0; j4 < 8; ++j4) {
      float4 t4 = qp[j4];
      qv[j4*4+0]=t4.x; qv[j4*4+1]=t4.y; qv[j4*4+2]=t4.z; qv[j4*4+3]=t4.w;
    }
  }
  float m = -INFINITY, lsum = 0.f;
  float acc[32];
#pragma unroll
  for (int d = 0; d < 32; ++d) acc[d] = 0.f;

  for (int j0 = 0; j0 < ns; j0 += 64) {
    const int nj = min(64, ns - j0);
    __syncthreads();
    // coalesced stage: 8 threads per key row (8 x float4 = 128B contiguous)
    {
      int jr = (int)threadIdx.x >> 3;
      const int c4 = ((int)threadIdx.x & 7) * 4;
#pragma unroll
      for (int pass = 0; pass < 2; ++pass, jr += 32) {
        if (jr < nj) {
          const size_t base = (size_t)(b*L_ + j0 + jr)*128 + h*32 + c4;
          *reinterpret_cast<float4*>(&Ks[jr][c4]) = *reinterpret_cast<const float4*>(k + base);
          *reinterpret_cast<float4*>(&Vs[jr][c4]) = *reinterpret_cast<const float4*>(v + base);
        }
      }
    }
    __syncthreads();
    if (active) {
      for (int j = 0; j < nj; ++j) {
        float d0=0.f, d1=0.f, d2=0.f, d3=0.f;
#pragma unroll
        for (int dd = 0; dd < 32; dd += 4) {
          d0 = fmaf(qv[dd+0], Ks[j][dd+0], d0);
          d1 = fmaf(qv[dd+1], Ks[j][dd+1], d1);
          d2 = fmaf(qv[dd+2], Ks[j][dd+2], d2);
          d3 = fmaf(qv[dd+3], Ks[j][dd+3], d3);
        }
        const float scr = (d0+d1) + (d2+d3);
        const float s2 = scr * scale;
        if (s2 > m) {                       // rare after warm-up (~ln ns times)
          const float ea = (m > -1e37f) ? __expf(m - s2) : 0.f;
          lsum *= ea;
#pragma unroll
          for (int dd = 0; dd < 32; ++dd) acc[dd] *= ea;
          m = s2;
        }
        const float p = __expf(s2 - m);
        lsum += p;
#pragma unroll
        for (int dd = 0; dd < 32; ++dd) acc[dd] = fmaf(p, Vs[j][dd], acc[dd]);
      }
    }
  }
  if (active) {
    const float inv = 1.0f / lsum;
    float* op = ao + (size_t)(b*L_+qi)*128 + h*32;
#pragma unroll
    for (int dd = 0; dd < 32; ++dd) op[dd] = acc[dd] * inv;
  }
}

// ---------------- LN(x + r)*g + b, in place into x ----------------
template<int D, bool GATED>
__global__ __launch_bounds__(D) void ln_res_kernel(
    float* __restrict__ x, const float* __restrict__ r,
    const float* __restrict__ gam, const float* __restrict__ bet,
    const int* __restrict__ nseg)
{
  const size_t row = blockIdx.x;
  if (GATED) {
    const int b = (int)(row >> 10), i = (int)(row & (L_-1));
    if (i >= nseg[b]) return;
  }
  const int d = threadIdx.x;
  float val = x[row*D + d] + r[row*D + d];
  float s = wave_reduce_sum(val);
  __shared__ float red[4];
  if constexpr (D == 128) {
    if ((d & 63) == 0) red[d >> 6] = s;
    __syncthreads();
    s = red[0] + red[1];
  }
  const float mean = s / (float)D;
  const float dv = val - mean;
  float s2 = wave_reduce_sum(dv*dv);
  if constexpr (D == 128) {
    if ((d & 63) == 0) red[2 + (d >> 6)] = s2;
    __syncthreads();
    s2 = red[2] + red[3];
  }
  x[row*D + d] = dv * rsqrtf(s2 / (float)D + 1e-5f) * gam[d] + bet[d];
}

// ---------------- segment mean pooling (invalid s: skip, stale never read) ---
__global__ __launch_bounds__(64) void pool_kernel(
    const float* __restrict__ h, const int* __restrict__ seg_start,
    const int* __restrict__ n_seg, float* __restrict__ mean)
{
  const int b = blockIdx.x >> 10;
  const int s = blockIdx.x & (L_-1);
  if (s >= n_seg[b]) return;
  const int d = threadIdx.x;
  const int j0 = seg_start[b*(L_+1)+s], j1 = seg_start[b*(L_+1)+s+1];
  float acc = 0.f;
  for (int j = j0; j < j1; ++j) acc += h[(size_t)(b*L_+j)*64 + d];
  mean[(size_t)(b*L_+s)*64 + d] = acc / (float)(j1 - j0);
}

// ---------------- final: pooled @ fin_w + fin_b ----------------
__global__ __launch_bounds__(128) void final_kernel(
    const float* __restrict__ g, const float* __restrict__ semb,
    const int* __restrict__ n_seg, const float* __restrict__ fin_w,
    const float* __restrict__ fin_b, float* __restrict__ out)
{
  const int b = blockIdx.x, d = threadIdx.x;
  const int ns = n_seg[b];
  __shared__ float pl[128];
  float pooled;
  if (ns == 1) pooled = semb[(size_t)(b*L_)*128 + d];
  else {
    float acc = 0.f;
    for (int i = 0; i < ns; ++i) acc += g[(size_t)(b*L_+i)*128 + d];
    pooled = acc / (float)ns;
  }
  pl[d] = pooled;
  __syncthreads();
  float o = fin_b[d];
#pragma unroll 8
  for (int k2 = 0; k2 < 128; ++k2) o = fmaf(pl[k2], fin_w[k2*128+d], o);
  out[b*128+d] = o;
}

extern "C" void kernel_launch(void* const* d_in, const int* in_sizes, int n_in,
                              void* d_out, int out_size, void* d_ws, size_t ws_size,
                              hipStream_t stream) {
  const float* pts     = (const float*)d_in[0];
  const float* fs      = (const float*)d_in[1];
  const float* ft      = (const float*)d_in[2];
  const float* w_space = (const float*)d_in[3];
  const float* b_space = (const float*)d_in[4];
  const float* w_time  = (const float*)d_in[5];
  const float* b_time  = (const float*)d_in[6];
  const float* w_fout  = (const float*)d_in[7];
  const float* b_fout  = (const float*)d_in[8];
  const float* w_gate  = (const float*)d_in[9];
  const float* b_gate  = (const float*)d_in[10];
  const float* seg_attn_w = (const float*)d_in[11];
  const float* seg_attn_b = (const float*)d_in[12];
  const float* seg_ln_g   = (const float*)d_in[13];
  const float* seg_ln_b   = (const float*)d_in[14];
  const float* seg_ff1_w  = (const float*)d_in[15];
  const float* seg_ff1_b  = (const float*)d_in[16];
  const float* seg_ff2_w  = (const float*)d_in[17];
  const float* seg_ff2_b  = (const float*)d_in[18];
  const float* glb_attn_w = (const float*)d_in[19];
  const float* glb_attn_b = (const float*)d_in[20];
  const float* glb_ln_g   = (const float*)d_in[21];
  const float* glb_ln_b   = (const float*)d_in[22];
  const float* glb_ff1_w  = (const float*)d_in[23];
  const float* glb_ff1_b  = (const float*)d_in[24];
  const float* glb_ff2_w  = (const float*)d_in[25];
  const float* glb_ff2_b  = (const float*)d_in[26];
  const float* up_w    = (const float*)d_in[27];
  const float* up_b    = (const float*)d_in[28];
  const float* fin_w   = (const float*)d_in[29];
  const float* fin_b   = (const float*)d_in[30];

  char* ws = (char*)d_ws;
  float* zx   = (float*)(ws);                         // 16384*64  = 4MB
  float* qb   = (float*)(ws + ((size_t)4  << 20));    // 16384*128 = 8MB
  float* kb   = (float*)(ws + ((size_t)12 << 20));    // 8MB
  float* vb   = (float*)(ws + ((size_t)20 << 20));    // 8MB (also reused as pooled-mean)
  float* aob  = (float*)(ws + ((size_t)28 << 20));    // 8MB
  float* xg   = (float*)(ws + ((size_t)36 << 20));    // 8MB
  float* semb = (float*)(ws + ((size_t)44 << 20));    // 8MB
  float* tmp  = qb;                                   // alias (disjoint lifetimes)
  int* boundary  = (int*)(ws + ((size_t)52 << 20));
  int* seg_id    = boundary + M_TOT;
  int* seg_start = seg_id + M_TOT;
  int* n_seg     = seg_start + B_*(L_+1);

  featurize_kernel<<<M_TOT, 64, 0, stream>>>(pts, fs, ft, w_space, b_space, w_time, b_time,
                                             w_fout, b_fout, w_gate, b_gate, zx, boundary);
  scan_kernel<<<B_, 1024, 0, stream>>>(boundary, seg_id, seg_start, n_seg);

  // ---- segment-level encoder (D=64, H=2, FF=128) ----
  for (int l = 0; l < 2; ++l) {
    const float* aw = seg_attn_w + (size_t)l*4*64*64;
    const float* ab = seg_attn_b + (size_t)l*4*64;
    gemm_kernel<64,64,false,false><<<256,256,0,stream>>>(zx, aw + 0*4096, ab + 0,   qb, nullptr);
    gemm_kernel<64,64,false,false><<<256,256,0,stream>>>(zx, aw + 1*4096, ab + 64,  kb, nullptr);
    gemm_kernel<64,64,false,false><<<256,256,0,stream>>>(zx, aw + 2*4096, ab + 128, vb, nullptr);
    seg_attn_kernel<<<(M_TOT*2)/256, 256, 0, stream>>>(qb, kb, vb, seg_id, seg_start, aob);
    gemm_kernel<64,64,false,false><<<256,256,0,stream>>>(aob, aw + 3*4096, ab + 192, tmp, nullptr);
    ln_res_kernel<64,false><<<M_TOT, 64, 0, stream>>>(zx, tmp, seg_ln_g + l*128, seg_ln_b + l*128, nullptr);
    gemm_kernel<128,64,true,false><<<256,256,0,stream>>>(zx, seg_ff1_w + (size_t)l*64*128, seg_ff1_b + l*128, tmp, nullptr);
    gemm_kernel<64,128,false,false><<<256,256,0,stream>>>(tmp, seg_ff2_w + (size_t)l*128*64, seg_ff2_b + l*64, aob, nullptr);
    ln_res_kernel<64,false><<<M_TOT, 64, 0, stream>>>(zx, aob, seg_ln_g + l*128 + 64, seg_ln_b + l*128 + 64, nullptr);
  }

  // ---- pooling + up-projection (gated past n_seg) ----
  pool_kernel<<<M_TOT, 64, 0, stream>>>(zx, seg_start, n_seg, vb);
  gemm_kernel<128,64,false,true><<<256,256,0,stream>>>(vb, up_w, up_b, semb, n_seg);
  hipMemcpyAsync(xg, semb, (size_t)M_TOT*128*4, hipMemcpyDeviceToDevice, stream);

  // ---- global-level encoder (D=128, H=4, FF=256), row-gated on n_seg ----
  for (int l = 0; l < 2; ++l) {
    const float* aw = glb_attn_w + (size_t)l*4*128*128;
    const float* ab = glb_attn_b + (size_t)l*4*128;
    gemm_kernel<128,128,false,true><<<256,256,0,stream>>>(xg, aw + 0*16384, ab + 0,   qb, n_seg);
    gemm_kernel<128,128,false,true><<<256,256,0,stream>>>(xg, aw + 1*16384, ab + 128, kb, n_seg);
    gemm_kernel<128,128,false,true><<<256,256,0,stream>>>(xg, aw + 2*16384, ab + 256, vb, n_seg);
    glb_attn_kernel<<<B_*4*4, 256, 0, stream>>>(qb, kb, vb, n_seg, aob);
    gemm_kernel<128,128,false,true><<<256,256,0,stream>>>(aob, aw + 3*16384, ab + 384, tmp, n_seg);
    ln_res_kernel<128,true><<<M_TOT, 128, 0, stream>>>(xg, tmp, glb_ln_g + l*256, glb_ln_b + l*256, n_seg);
    gemm_kernel<256,128,true,true><<<256,256,0,stream>>>(xg, glb_ff1_w + (size_t)l*128*256, glb_ff1_b + l*256, tmp, n_seg);
    gemm_kernel<128,256,false,true><<<256,256,0,stream>>>(tmp, glb_ff2_w + (size_t)l*256*128, glb_ff2_b + l*128, aob, n_seg);
    ln_res_kernel<128,true><<<M_TOT, 128, 0, stream>>>(xg, aob, glb_ln_g + l*256 + 128, glb_ln_b + l*256 + 128, n_seg);
  }

  final_kernel<<<B_, 128, 0, stream>>>(xg, semb, n_seg, fin_w, fin_b, (float*)d_out);
}